// Round 1
// 1027.979 us; speedup vs baseline: 1.2871x; 1.2871x over previous
//
#include <hip/hip_runtime.h>
#include <hip/hip_bf16.h>

typedef __hip_bfloat16 bf16;
typedef __attribute__((ext_vector_type(8))) short short8;   // 8 bf16 = 4 VGPRs (MFMA A/B frag)
typedef __attribute__((ext_vector_type(4))) float f32x4;    // MFMA C/D frag

#define S_TOK   2048
#define NROWS   4096        // B*S
#define NH      16
#define QKD     192
#define NOPE_   128
#define ROPE_   64
#define VDIM_   128
#define RANK    512
#define SCALE_F 0.07216878364870323f   // 192^-0.5
#define NEG_BIG -3.0e38f

__device__ __forceinline__ float bl(unsigned u){ union{unsigned i; float f;} t; t.i = u << 16; return t.f; }
__device__ __forceinline__ float bh(unsigned u){ union{unsigned i; float f;} t; t.i = u & 0xffff0000u; return t.f; }
__device__ __forceinline__ unsigned short f2b(float f){
  bf16 h = __float2bfloat16(f);
  return *reinterpret_cast<unsigned short*>(&h);
}
__device__ __forceinline__ void store4(bf16* p, float a, float b, float c, float d){
  ushort4 u; u.x=f2b(a); u.y=f2b(b); u.z=f2b(c); u.w=f2b(d);
  *(ushort4*)p = u;
}
union U8 { uint4 u; short8 s; };
#define MFMA16x32(a,b,c) __builtin_amdgcn_mfma_f32_16x16x32_bf16(a,b,c,0,0,0)

// async global -> LDS DMA, 16 B per lane. LDS dest is wave-uniform base +
// lane*16 (linear); source is per-lane (pre-swizzled where the LDS layout
// needs it — rule: swizzle source+read, keep dest linear).
__device__ __forceinline__ void gload16(const unsigned short* g, unsigned short* l)
{
  __builtin_amdgcn_global_load_lds(
      (const __attribute__((address_space(1))) unsigned int*)g,
      (__attribute__((address_space(3))) unsigned int*)l,
      16, 0, 0);
}

// ---------------------------------------------------------------------------
// cvt_bf16: f32 -> bf16 elementwise (n multiple of 1024)
// ---------------------------------------------------------------------------
__global__ __launch_bounds__(256) void cvt_bf16(const float* __restrict__ src,
                                                bf16* __restrict__ dst, int n)
{
  int g = (blockIdx.x * 256 + threadIdx.x) * 4;
  if (g < n) {
    float4 v = *(const float4*)(src + g);
    store4(dst + g, v.x, v.y, v.z, v.w);
  }
}

// ---------------------------------------------------------------------------
// tr_wbk: wkv_b K-half (h, d<128, c) f32 -> wbkT (h, c, d) bf16.  grid (2,8,16)
// ---------------------------------------------------------------------------
__global__ __launch_bounds__(256) void tr_wbk(const float* __restrict__ wkvb,
                                              bf16* __restrict__ wbkT)
{
  const int d0 = blockIdx.x << 6, c0 = blockIdx.y << 6, h = blockIdx.z;
  const int tid = threadIdx.x;
  __shared__ float tile[64*65];
  #pragma unroll
  for (int j = 0; j < 16; ++j) {
    int idx = tid + j*256; int r = idx >> 6, c = idx & 63;   // r=d, c=c
    tile[r*65 + c] = wkvb[((long)(h*256 + d0 + r))*512 + c0 + c];
  }
  __syncthreads();
  #pragma unroll
  for (int j = 0; j < 16; ++j) {
    int idx = tid + j*256; int r = idx >> 6, cc = idx & 63;  // r=c, cc=d
    ((unsigned short*)wbkT)[(long)h*65536 + (long)(c0 + r)*128 + d0 + cc] = f2b(tile[cc*65 + r]);
  }
}

// ---------------------------------------------------------------------------
// wbv_cvt: wkv_b V-half (16 x 128 x 512 f32) -> bf16 (same orientation)
// ---------------------------------------------------------------------------
__global__ __launch_bounds__(256) void wbv_cvt(const float* __restrict__ wkvb,
                                               bf16* __restrict__ wbv)
{
  int g = blockIdx.x * 256 + threadIdx.x;       // 1,048,576
  int h = g >> 16, rem = g & 65535;
  ((unsigned short*)wbv)[g] = f2b(wkvb[((long)(h*256 + NOPE_))*512 + rem]);
}

// ---------------------------------------------------------------------------
// MFMA GEMM: C[M,N] = A[M,K] @ W[N,K]^T, bf16 A/W, TOUT out.
// M,N multiples of 64; K multiple of 64. grid (N/64, M/64, Z), 256 thr.
// LDS blocked layout: slot = c8*65 + row (8 K-chunks of 8 halves x 64 rows,
// +1 row pad per chunk) -> frag ds_read_b128 are 2-way max (free).
// ---------------------------------------------------------------------------
template<typename TOUT>
__global__ __launch_bounds__(256) void gemm_mfma(
    const bf16* __restrict__ A, const bf16* __restrict__ W, TOUT* __restrict__ C,
    int K, int lda, int ldw, int ldc, long azs, long wzs, long czs)
{
  A += (long)blockIdx.z * azs;
  W += (long)blockIdx.z * wzs;
  C += (long)blockIdx.z * czs;
  __shared__ __align__(16) unsigned short As[8*65*8];   // 8320 B
  __shared__ __align__(16) unsigned short Ws[8*65*8];
  const int tid = threadIdx.x;
  const int m0 = blockIdx.y << 6, n0 = blockIdx.x << 6;
  const int w = tid >> 6, lane = tid & 63;
  const int quad = lane >> 4, l16 = lane & 15;

  const int r0 = tid >> 3, c80 = tid & 7;   // staging coords: f=tid -> (r,c8)
  const int r1 = (tid + 256) >> 3;          // second slot (same c8)

  f32x4 acc[4];
  #pragma unroll
  for (int i = 0; i < 4; ++i) acc[i] = (f32x4){0.f,0.f,0.f,0.f};

  for (int k0 = 0; k0 < K; k0 += 64) {
    uint4 a0 = *(const uint4*)(A + (long)(m0 + r0)*lda + k0 + c80*8);
    uint4 a1 = *(const uint4*)(A + (long)(m0 + r1)*lda + k0 + c80*8);
    uint4 w0 = *(const uint4*)(W + (long)(n0 + r0)*ldw + k0 + c80*8);
    uint4 w1 = *(const uint4*)(W + (long)(n0 + r1)*ldw + k0 + c80*8);
    __syncthreads();   // previous stage's reads done
    *(uint4*)(As + (c80*65 + r0)*8) = a0;
    *(uint4*)(As + (c80*65 + r1)*8) = a1;
    *(uint4*)(Ws + (c80*65 + r0)*8) = w0;
    *(uint4*)(Ws + (c80*65 + r1)*8) = w1;
    __syncthreads();
    #pragma unroll
    for (int kc = 0; kc < 2; ++kc) {
      const int kcq = kc*4 + quad;
      U8 af; af.u = *(const uint4*)(As + (kcq*65 + w*16 + l16)*8);
      #pragma unroll
      for (int nt = 0; nt < 4; ++nt) {
        U8 bf_; bf_.u = *(const uint4*)(Ws + (kcq*65 + nt*16 + l16)*8);
        acc[nt] = MFMA16x32(af.s, bf_.s, acc[nt]);
      }
    }
  }
  #pragma unroll
  for (int nt = 0; nt < 4; ++nt) {
    #pragma unroll
    for (int i = 0; i < 4; ++i) {
      long row = m0 + w*16 + quad*4 + i;
      TOUT v;
      if constexpr (sizeof(TOUT) == 2) v = __float2bfloat16(acc[nt][i]);
      else                             v = acc[nt][i];
      C[row*ldc + n0 + nt*16 + l16] = v;
    }
  }
}

// ---------------------------------------------------------------------------
// kvprep (bf16 in): RMSNorm first 512 -> ckv (bf16), RoPE last 64 -> kpe (bf16)
// ---------------------------------------------------------------------------
__global__ __launch_bounds__(64) void kvprep(
    const bf16* __restrict__ kvbuf, const float* __restrict__ wnorm,
    const float* __restrict__ cosb, const float* __restrict__ sinb,
    bf16* __restrict__ ckv, bf16* __restrict__ kpe)
{
  const int row = blockIdx.x;
  const int s = row & (S_TOK - 1);
  const int lane = threadIdx.x;
  const unsigned short* kr = (const unsigned short*)kvbuf + (long)row * 576;
  uint4 u = *(const uint4*)(kr + lane*8);
  float v[8] = { bl(u.x), bh(u.x), bl(u.y), bh(u.y), bl(u.z), bh(u.z), bl(u.w), bh(u.w) };
  float ss = 0.f;
  #pragma unroll
  for (int j = 0; j < 8; ++j) ss += v[j]*v[j];
  #pragma unroll
  for (int off = 32; off > 0; off >>= 1) ss += __shfl_down(ss, off);
  ss = __shfl(ss, 0);
  const float scl = rsqrtf(ss * (1.0f/512.0f) + 1e-6f);
  float4 w0 = *(const float4*)(wnorm + lane*8);
  float4 w1 = *(const float4*)(wnorm + lane*8 + 4);
  bf16* cd = ckv + (long)row*512 + lane*8;
  store4(cd,   v[0]*scl*w0.x, v[1]*scl*w0.y, v[2]*scl*w0.z, v[3]*scl*w0.w);
  store4(cd+4, v[4]*scl*w1.x, v[5]*scl*w1.y, v[6]*scl*w1.z, v[7]*scl*w1.w);
  if (lane < 32) {
    unsigned pe = *(const unsigned*)(kr + 512 + 2*lane);
    float xe = bl(pe), xo = bh(pe);
    float c = cosb[s*32 + lane], sn = sinb[s*32 + lane];
    ushort2 o; o.x = f2b(xe*c - xo*sn); o.y = f2b(xe*sn + xo*c);
    *(ushort2*)((unsigned short*)kpe + (long)row*64 + 2*lane) = o;
  }
}

// ---------------------------------------------------------------------------
// ropeq (bf16 in): RoPE q_pe slice of qbuf -> qpe (bf16, 4096 x 16*64)
// ---------------------------------------------------------------------------
__global__ __launch_bounds__(256) void ropeq(
    const bf16* __restrict__ qbuf, const float* __restrict__ cosb,
    const float* __restrict__ sinb, bf16* __restrict__ qpe)
{
  int gid = blockIdx.x * 256 + threadIdx.x;       // 4096*16*32
  int row = gid >> 9; int rem = gid & 511;
  int h = rem >> 5, i = rem & 31;
  int s = row & (S_TOK - 1);
  unsigned pp = *(const unsigned*)((const unsigned short*)qbuf + (long)row*3072 + h*QKD + NOPE_ + 2*i);
  float xe = bl(pp), xo = bh(pp);
  float c = cosb[s*32 + i], sn = sinb[s*32 + i];
  ushort2 u; u.x = f2b(xe*c - xo*sn); u.y = f2b(xe*sn + xo*c);
  *(ushort2*)((unsigned short*)qpe + (long)row*1024 + h*64 + 2*i) = u;
}

// ---------------------------------------------------------------------------
// tr64: ckv (b, t, c) -> ckvT TILED: [b][t>>5][c(512)][t&31], bf16.
// Tiled so the attention V^T stage is one linear 32 KB block per 32-token
// tile (perfectly coalesced global_load_lds).
// ---------------------------------------------------------------------------
__global__ __launch_bounds__(256) void tr64(const bf16* __restrict__ ckv,
                                            bf16* __restrict__ ckvT)
{
  const int t0 = blockIdx.x << 6, c0 = blockIdx.y << 6, b = blockIdx.z;
  const int tid = threadIdx.x;
  __shared__ unsigned short tile[64*65];
  const unsigned short* src = (const unsigned short*)ckv + (long)b*S_TOK*512;
  #pragma unroll
  for (int j = 0; j < 16; ++j) {
    int idx = tid + j*256; int r = idx >> 6, c = idx & 63;
    tile[r*65 + c] = src[(long)(t0+r)*512 + c0 + c];
  }
  __syncthreads();
  unsigned short* dst = (unsigned short*)ckvT + (long)b*512*S_TOK;
  #pragma unroll
  for (int j = 0; j < 16; ++j) {
    int idx = tid + j*256; int r = idx >> 6, t = idx & 63;   // r: c offset, t: token offset
    int tt = t0 + t;
    dst[((long)(tt >> 5)*512 + (c0 + r))*32 + (tt & 31)] = tile[t*65 + r];
  }
}

// ---------------------------------------------------------------------------
// MFMA flash attention v4 — all staging via coalesced global_load_lds DMA.
// grid = 512 = (b:2, h:16, qpair:16); block does qt=31-qp then qt=qp (66 tiles).
//
// LDS granule map (granule = 16 B = 8 halves), single smem arena:
//   [0,2048)    ckv QK tile : g(t,c8)  = t*64 + (c8 ^ (t&7)),  t<32, c8<64
//   [2048,2304) kpe tile    : 2048 + t*8 + (c8p ^ (t&7)),      c8p<8
//   [2304,4352) V^T tile    : 2304 + c*4 + tg,                 c<512, tg<4
// DMA dest is linear (granule = staging index u); the XOR swizzle is applied
// to the *global source* address, so QK B-frag ds_read_b128 land on 8
// distinct 16B slots per 128B (conflict-free floor). V^T tile comes from the
// tiled ckvT global layout -> pure linear DMA, reads conflict-free unpadded.
// ---------------------------------------------------------------------------
__global__ __launch_bounds__(256, 2) void attn_mfma(
    const bf16* __restrict__ qlat,   // (4096, 16*512)
    const bf16* __restrict__ qpe,    // (4096, 16*64)
    const bf16* __restrict__ ckv,    // (4096, 512)
    const bf16* __restrict__ kpe,    // (4096, 64)
    const bf16* __restrict__ ckvT,   // (B, 64 tiles, 512, 32)  [tiled]
    const bf16* __restrict__ wbv,    // (16, 128, 512)
    bf16* __restrict__ obuf)         // (4096, 2048) bf16
{
  const int idx = blockIdx.x;
  const int qp = idx & 15;
  const int h  = (idx >> 4) & 15;
  const int b  = idx >> 8;
  const int tid = threadIdx.x;
  const int w = tid >> 6, lane = tid & 63;
  const int quad = lane >> 4, l16 = lane & 15;

  __shared__ __align__(16) unsigned short smem[4352 * 8];    // 69,632 B
  __shared__ __align__(16) unsigned short P_s[4 * 16 * 40];  //  5,120 B

  const unsigned short* ckv_b  = (const unsigned short*)ckv  + (long)b*S_TOK*512;
  const unsigned short* kpe_b  = (const unsigned short*)kpe  + (long)b*S_TOK*64;
  const unsigned short* ckvT_b = (const unsigned short*)ckvT + (long)b*512*S_TOK;
  unsigned short* Pw = P_s + w*640;

  #pragma unroll 1
  for (int half = 0; half < 2; ++half) {
    const int qt = half ? qp : (31 - qp);      // big q-tile first
    const int q0 = qt << 6;

    // ---- Q fragments: A[m=l16][k=quad*8+j], 18 K-chunks (512 lat + 64 pe)
    const long qrow = (long)b*S_TOK + q0 + w*16 + l16;
    short8 qf[18];
    {
      const unsigned short* qlp = (const unsigned short*)qlat + qrow*8192 + h*512 + quad*8;
      const unsigned short* qpp = (const unsigned short*)qpe  + qrow*1024 + h*64  + quad*8;
      #pragma unroll
      for (int kc = 0; kc < 16; ++kc) { U8 t; t.u = *(const uint4*)(qlp + kc*32); qf[kc] = t.s; }
      { U8 t; t.u = *(const uint4*)(qpp);      qf[16] = t.s; }
      { U8 t; t.u = *(const uint4*)(qpp + 32); qf[17] = t.s; }
    }

    f32x4 acc[32];
    #pragma unroll
    for (int i = 0; i < 32; ++i) acc[i] = (f32x4){0.f,0.f,0.f,0.f};
    float mi[4] = {NEG_BIG,NEG_BIG,NEG_BIG,NEG_BIG};
    float li[4] = {0.f,0.f,0.f,0.f};

    const int myqmax = q0 + w*16 + 15;
    const int ntiles = (q0 >> 5) + 2;

    for (int tile = 0; tile < ntiles; ++tile) {
      const int t0 = tile << 5;
      // ---- async-stage K-tile: all coalesced 16B-per-lane DMA ----
      #pragma unroll
      for (int j = 0; j < 8; ++j) {                       // ckv: 1 row / wave-instr
        const int u = tid + j*256;
        const int t = u >> 6, c8 = (u & 63) ^ (t & 7);
        gload16(ckv_b + (long)(t0 + t)*512 + c8*8, smem + (j*256 + w*64)*8);
      }
      { const int t = tid >> 3, c8p = (tid & 7) ^ (t & 7); // kpe: 8 rows / wave-instr
        gload16(kpe_b + (long)(t0 + t)*64 + c8p*8, smem + (2048 + w*64)*8); }
      {
        const unsigned short* vt = ckvT_b + (long)tile * 16384;  // V^T: pure linear
        #pragma unroll
        for (int j = 0; j < 8; ++j)
          gload16(vt + (long)(tid + j*256)*8, smem + (2304 + j*256 + w*64)*8);
      }
      __syncthreads();   // drains vmcnt: DMA complete, previous reads done

      const bool active = (t0 <= myqmax);
      if (active) {
        // ---- scores: two 16x16 C-tiles (token halves) ----
        f32x4 sc0 = (f32x4){0.f,0.f,0.f,0.f}, sc1 = sc0;
        #pragma unroll
        for (int kc = 0; kc < 18; ++kc) {
          const int kcq = kc*4 + quad;
          int g0, g1;
          if (kc < 16) {
            g0 = l16*64        + (kcq ^ (l16 & 7));
            g1 = (16+l16)*64   + (kcq ^ (l16 & 7));
          } else {
            g0 = 2048 + l16*8      + ((kcq & 7) ^ (l16 & 7));
            g1 = 2048 + (16+l16)*8 + ((kcq & 7) ^ (l16 & 7));
          }
          U8 b0; b0.u = *(const uint4*)(smem + g0*8);
          U8 b1; b1.u = *(const uint4*)(smem + g1*8);
          sc0 = MFMA16x32(qf[kc], b0.s, sc0);
          sc1 = MFMA16x32(qf[kc], b1.s, sc1);
        }
        // ---- online softmax (C rows = quad*4+i, cols = l16 / 16+l16) ----
        float s0[4], s1[4], mx[4];
        #pragma unroll
        for (int i = 0; i < 4; ++i) {
          int qg = q0 + w*16 + quad*4 + i;
          s0[i] = (t0 + l16      <= qg) ? sc0[i]*SCALE_F : NEG_BIG;
          s1[i] = (t0 + 16 + l16 <= qg) ? sc1[i]*SCALE_F : NEG_BIG;
          mx[i] = fmaxf(mi[i], fmaxf(s0[i], s1[i]));
        }
        #pragma unroll
        for (int d = 1; d < 16; d <<= 1) {
          #pragma unroll
          for (int i = 0; i < 4; ++i) mx[i] = fmaxf(mx[i], __shfl_xor(mx[i], d));
        }
        float al[4], rs[4];
        #pragma unroll
        for (int i = 0; i < 4; ++i) {
          al[i] = __expf(mi[i] - mx[i]); mi[i] = mx[i];
          float p0 = __expf(s0[i] - mx[i]);
          float p1 = __expf(s1[i] - mx[i]);
          rs[i] = p0 + p1;
          Pw[(quad*4+i)*40 + l16]      = f2b(p0);
          Pw[(quad*4+i)*40 + 16 + l16] = f2b(p1);
        }
        #pragma unroll
        for (int d = 1; d < 16; d <<= 1) {
          #pragma unroll
          for (int i = 0; i < 4; ++i) rs[i] += __shfl_xor(rs[i], d);
        }
        #pragma unroll
        for (int i = 0; i < 4; ++i) li[i] = li[i]*al[i] + rs[i];
        #pragma unroll
        for (int nt = 0; nt < 32; ++nt) {
          #pragma unroll
          for (int i = 0; i < 4; ++i) acc[nt][i] *= al[i];
        }
        // ---- PV: A = P (LDS roundtrip), B = V^T tile from smem ----
        U8 ap; ap.u = *(const uint4*)(Pw + l16*40 + quad*8);
        #pragma unroll
        for (int nt = 0; nt < 32; ++nt) {
          U8 bv; bv.u = *(const uint4*)(smem + (2304 + (nt*16 + l16)*4 + quad)*8);
          acc[nt] = MFMA16x32(ap.s, bv.s, acc[nt]);
        }
      }
      __syncthreads();   // smem reads done before next tile's DMA
    }

    // ---- epilogue: normalize, o_lat -> LDS (A layout), o = o_lat @ wb_v^T ----
    float linv[4];
    #pragma unroll
    for (int i = 0; i < 4; ++i) linv[i] = 1.0f / li[i];
    const int pass = w >> 1;
    unsigned short* ola = smem + (w & 1) * 16 * 520;
    #pragma unroll 1
    for (int p = 0; p < 2; ++p) {
      if (pass == p) {
        #pragma unroll
        for (int nt = 0; nt < 32; ++nt) {
          #pragma unroll
          for (int i = 0; i < 4; ++i)
            ola[(quad*4+i)*520 + nt*16 + l16] = f2b(acc[nt][i] * linv[i]);
        }
      }
      __syncthreads();
      if (pass == p) {
        f32x4 oc[8];
        #pragma unroll
        for (int nt = 0; nt < 8; ++nt) oc[nt] = (f32x4){0.f,0.f,0.f,0.f};
        #pragma unroll
        for (int kc = 0; kc < 16; ++kc) {
          U8 a; a.u = *(const uint4*)(ola + l16*520 + kc*32 + quad*8);
          #pragma unroll
          for (int nt = 0; nt < 8; ++nt) {
            U8 bw; bw.u = *(const uint4*)((const unsigned short*)wbv +
                           (long)(h*128 + nt*16 + l16)*512 + kc*32 + quad*8);
            oc[nt] = MFMA16x32(a.s, bw.s, oc[nt]);
          }
        }
        #pragma unroll
        for (int nt = 0; nt < 8; ++nt) {
          #pragma unroll
          for (int i = 0; i < 4; ++i)
            ((unsigned short*)obuf)[((long)b*S_TOK + q0 + w*16 + quad*4 + i)*2048
                                    + h*128 + nt*16 + l16] = f2b(oc[nt][i]);
        }
      }
      __syncthreads();
    }
  }
}

// ---------------------------------------------------------------------------
extern "C" void kernel_launch(void* const* d_in, const int* in_sizes, int n_in,
                              void* d_out, int out_size, void* d_ws, size_t ws_size,
                              hipStream_t stream)
{
  const float* x     = (const float*)d_in[0];
  const float* wq    = (const float*)d_in[1];
  const float* wkv_a = (const float*)d_in[2];
  const float* kvnw  = (const float*)d_in[3];
  const float* wkv_b = (const float*)d_in[4];
  const float* wo    = (const float*)d_in[5];
  const float* cosb  = (const float*)d_in[6];
  const float* sinb  = (const float*)d_in[7];
  float* out = (float*)d_out;

  size_t off = 0;
  char* wsb = (char*)d_ws;
  bf16* xb    = (bf16*)(wsb + off); off += (size_t)NROWS * 2048 * 2;   // 16.8 MB
  bf16* wqb   = (bf16*)(wsb + off); off += (size_t)3072 * 2048 * 2;    // 12.6 MB
  bf16* wab   = (bf16*)(wsb + off); off += (size_t)576  * 2048 * 2;    //  2.4 MB
  bf16* wob   = (bf16*)(wsb + off); off += (size_t)2048 * 2048 * 2;    //  8.4 MB
  bf16* wbkT  = (bf16*)(wsb + off); off += (size_t)NH * 512 * 128 * 2; //  2.1 MB
  bf16* wbvb  = (bf16*)(wsb + off); off += (size_t)1048576 * 2;        //  2.1 MB
  bf16* qbuf  = (bf16*)(wsb + off); off += (size_t)NROWS * 3072 * 2;   // 25.2 MB
  bf16* kvbuf = (bf16*)(wsb + off); off += (size_t)NROWS * 576  * 2;   //  4.7 MB
  bf16* ckvb  = (bf16*)(wsb + off); off += (size_t)NROWS * 512  * 2;   //  4.2 MB
  bf16* kpeb  = (bf16*)(wsb + off); off += (size_t)NROWS * 64   * 2;   //  0.5 MB
  bf16* qpeb  = (bf16*)(wsb + off); off += (size_t)NROWS * 1024 * 2;   //  8.4 MB
  bf16* qlatb = (bf16*)(wsb + off); off += (size_t)NROWS * 8192 * 2;   // 67.1 MB
  bf16* ckvT  = (bf16*)(wsb + off); off += (size_t)NROWS * 512  * 2;   //  4.2 MB (tiled)
  bf16* obuf  = (bf16*)(wsb + off); off += (size_t)NROWS * 2048 * 2;   // 16.8 MB

  dim3 blk(256);
  // input/weight conversions
  cvt_bf16<<<dim3(8388608/1024),  blk, 0, stream>>>(x,     xb,  8388608);
  cvt_bf16<<<dim3(6291456/1024),  blk, 0, stream>>>(wq,    wqb, 6291456);
  cvt_bf16<<<dim3(1179648/1024),  blk, 0, stream>>>(wkv_a, wab, 1179648);
  cvt_bf16<<<dim3(4194304/1024),  blk, 0, stream>>>(wo,    wob, 4194304);
  tr_wbk<<<dim3(2, 8, NH), blk, 0, stream>>>(wkv_b, wbkT);
  wbv_cvt<<<dim3(4096), blk, 0, stream>>>(wkv_b, wbvb);
  // q = x @ wq^T
  gemm_mfma<bf16><<<dim3(3072/64, NROWS/64, 1), blk, 0, stream>>>(
      xb, wqb, qbuf, 2048, 2048, 2048, 3072, 0, 0, 0);
  ropeq<<<dim3(8192), blk, 0, stream>>>(qbuf, cosb, sinb, qpeb);
  // kv = x @ wkv_a^T
  gemm_mfma<bf16><<<dim3(576/64, NROWS/64, 1), blk, 0, stream>>>(
      xb, wab, kvbuf, 2048, 2048, 2048, 576, 0, 0, 0);
  kvprep<<<dim3(NROWS), dim3(64), 0, stream>>>(kvbuf, kvnw, cosb, sinb, ckvb, kpeb);
  tr64<<<dim3(S_TOK/64, 512/64, 2), blk, 0, stream>>>(ckvb, ckvT);
  // q_lat[h] = q_nope[:,h] @ wbkT[h]^T   (wbkT rows are c, cols d -> mode-0)
  gemm_mfma<bf16><<<dim3(512/64, NROWS/64, NH), blk, 0, stream>>>(
      qbuf, wbkT, qlatb, 128, 3072, 128, 8192,
      (long)QKD, (long)512*128, (long)512);
  // MFMA flash attention (+ fused o_lat @ wb_v^T)
  attn_mfma<<<dim3(512), blk, 0, stream>>>(qlatb, qpeb, ckvb, kpeb, ckvT, wbvb, obuf);
  // out = o @ wo^T (f32 out)
  gemm_mfma<float><<<dim3(2048/64, NROWS/64, 1), blk, 0, stream>>>(
      obuf, wob, out, 2048, 2048, 2048, 2048, 0, 0, 0);
}